// Round 1
// baseline (184.429 us; speedup 1.0000x reference)
//
#include <hip/hip_runtime.h>

#define BSg   32
#define NAg   128
#define NEg   16256
#define EMBg  64
#define H1g   256
#define TILE_E 64
#define NTILES 254   // NE / TILE_E = 16256/64

typedef __attribute__((ext_vector_type(8))) short  short8;
typedef __attribute__((ext_vector_type(4))) float  f32x4;

__device__ __forceinline__ unsigned int f2bf(float x) {
    union { float f; unsigned int u; } v; v.f = x;
    return (v.u + 0x7FFFu + ((v.u >> 16) & 1u)) >> 16;   // RNE bf16
}
__device__ __forceinline__ unsigned int pack2(float a, float b) {
    return f2bf(a) | (f2bf(b) << 16);
}

// ---- pack mlp1 weights fp32 -> bf16 in MFMA-B-fragment layout [K/8][N][8] ----
__global__ void pack_weights(const float* __restrict__ w1, const float* __restrict__ w2,
                             unsigned short* __restrict__ w1p, unsigned short* __restrict__ w2p)
{
    int i = blockIdx.x * 256 + threadIdx.x;
    if (i < 320 * 256) {
        int k = i >> 8, n = i & 255;
        w1p[(k >> 3) * (256 * 8) + n * 8 + (k & 7)] = (unsigned short)f2bf(w1[i]);
    }
    if (i < 256 * 64) {
        int k = i >> 6, n = i & 63;
        w2p[(k >> 3) * (64 * 8) + n * 8 + (k & 7)] = (unsigned short)f2bf(w2[i]);
    }
}

// ---- edge pipeline: conv -> MLP1 (bf16 MFMA) -> scatter-add ----
// A tile: 64 edges x K=320 (256 conv outputs + 64 x_last[src]), bf16 in LDS.
// LDS row stride 328 (pad 8) -> 656B rows: bank stride 4, conflict-free-ish.
__global__ __launch_bounds__(256) void edge_kernel(
    const float* __restrict__ x0, const float* __restrict__ x_last,
    const float* __restrict__ edge_attr, const float* __restrict__ conv_w,
    const float* __restrict__ conv_b, const unsigned short* __restrict__ w1p,
    const float* __restrict__ b1, const unsigned short* __restrict__ w2p,
    const float* __restrict__ b2, const int* __restrict__ edge_idx,
    float* __restrict__ agg)
{
    __shared__ unsigned short lfA[TILE_E * 328];   // 41.98 KB, reused for C1 (stride 264)
    __shared__ int dstS[TILE_E];

    const int tid = threadIdx.x;
    const int b   = blockIdx.x / NTILES;
    const int et  = blockIdx.x % NTILES;
    const int e0  = et * TILE_E;

    // ---------- build A tile (4 threads per edge) ----------
    {
        const int el = tid >> 2, t4 = tid & 3;
        const int e  = e0 + el;
        const int src = edge_idx[2 * e];
        if (t4 == 0) dstS[el] = edge_idx[2 * e + 1];

        const float4* nfp = (const float4*)(x0        + (((size_t)b * NAg + src) << 5) + (t4 << 3));
        const float4* eap = (const float4*)(edge_attr + (((size_t)b * NEg + e)   << 5) + (t4 << 3));
        float4 nf0 = nfp[0], nf1 = nfp[1];
        float4 ea0 = eap[0], ea1 = eap[1];

        #pragma unroll
        for (int o = 0; o < 8; ++o) {
            const float w0 = conv_w[2 * o], w1v = conv_w[2 * o + 1], cb = conv_b[o];
            float y0 = fmaxf(fmaf(w0, nf0.x, fmaf(w1v, ea0.x, cb)), 0.f);
            float y1 = fmaxf(fmaf(w0, nf0.y, fmaf(w1v, ea0.y, cb)), 0.f);
            float y2 = fmaxf(fmaf(w0, nf0.z, fmaf(w1v, ea0.z, cb)), 0.f);
            float y3 = fmaxf(fmaf(w0, nf0.w, fmaf(w1v, ea0.w, cb)), 0.f);
            float y4 = fmaxf(fmaf(w0, nf1.x, fmaf(w1v, ea1.x, cb)), 0.f);
            float y5 = fmaxf(fmaf(w0, nf1.y, fmaf(w1v, ea1.y, cb)), 0.f);
            float y6 = fmaxf(fmaf(w0, nf1.z, fmaf(w1v, ea1.z, cb)), 0.f);
            float y7 = fmaxf(fmaf(w0, nf1.w, fmaf(w1v, ea1.w, cb)), 0.f);
            uint4 pk;
            pk.x = pack2(y0, y1); pk.y = pack2(y2, y3);
            pk.z = pack2(y4, y5); pk.w = pack2(y6, y7);
            *(uint4*)&lfA[el * 328 + o * 32 + t4 * 8] = pk;
        }
        {
            const float4* lsp = (const float4*)(x_last + (((size_t)b * NAg + src) << 6) + (t4 << 4));
            float4 l0 = lsp[0], l1 = lsp[1], l2 = lsp[2], l3 = lsp[3];
            uint4 pa, pb;
            pa.x = pack2(l0.x, l0.y); pa.y = pack2(l0.z, l0.w);
            pa.z = pack2(l1.x, l1.y); pa.w = pack2(l1.z, l1.w);
            pb.x = pack2(l2.x, l2.y); pb.y = pack2(l2.z, l2.w);
            pb.z = pack2(l3.x, l3.y); pb.w = pack2(l3.z, l3.w);
            *(uint4*)&lfA[el * 328 + 256 + t4 * 16]     = pa;
            *(uint4*)&lfA[el * 328 + 256 + t4 * 16 + 8] = pb;
        }
    }
    __syncthreads();

    const int wave = tid >> 6, lane = tid & 63;
    const int llo = lane & 15, lhi = lane >> 4;
    const int colbase = wave * 64;

    // ---------- GEMM1: [64x320] @ [320x256], wave w owns cols w*64..w*64+63 ----------
    f32x4 acc[4][4];
    #pragma unroll
    for (int m = 0; m < 4; ++m)
        #pragma unroll
        for (int n = 0; n < 4; ++n)
            acc[m][n] = (f32x4){0.f, 0.f, 0.f, 0.f};

    #pragma unroll
    for (int ks = 0; ks < 10; ++ks) {
        short8 af[4], bf[4];
        #pragma unroll
        for (int m = 0; m < 4; ++m)
            af[m] = *(const short8*)&lfA[(m * 16 + llo) * 328 + ks * 32 + lhi * 8];
        #pragma unroll
        for (int n = 0; n < 4; ++n)
            bf[n] = *(const short8*)&w1p[((ks * 4 + lhi) * H1g + colbase + n * 16 + llo) * 8];
        #pragma unroll
        for (int m = 0; m < 4; ++m)
            #pragma unroll
            for (int n = 0; n < 4; ++n)
                acc[m][n] = __builtin_amdgcn_mfma_f32_16x16x32_bf16(af[m], bf[n], acc[m][n], 0, 0, 0);
    }

    float bias1[4];
    #pragma unroll
    for (int n = 0; n < 4; ++n) bias1[n] = b1[colbase + n * 16 + llo];

    __syncthreads();   // all waves done reading A before overwrite

    // write C1 = relu(acc + b1) as bf16 into LDS, row stride 264
    #pragma unroll
    for (int m = 0; m < 4; ++m)
        #pragma unroll
        for (int n = 0; n < 4; ++n)
            #pragma unroll
            for (int i = 0; i < 4; ++i) {
                float v = fmaxf(acc[m][n][i] + bias1[n], 0.f);
                lfA[(m * 16 + lhi * 4 + i) * 264 + colbase + n * 16 + llo] = (unsigned short)f2bf(v);
            }
    __syncthreads();

    // ---------- GEMM2: [64x256] @ [256x64], wave w owns rows w*16..w*16+15 ----------
    f32x4 acc2[4];
    #pragma unroll
    for (int n = 0; n < 4; ++n) acc2[n] = (f32x4){0.f, 0.f, 0.f, 0.f};

    #pragma unroll
    for (int ks = 0; ks < 8; ++ks) {
        short8 a2 = *(const short8*)&lfA[(wave * 16 + llo) * 264 + ks * 32 + lhi * 8];
        #pragma unroll
        for (int n = 0; n < 4; ++n) {
            short8 b2f = *(const short8*)&w2p[((ks * 4 + lhi) * EMBg + n * 16 + llo) * 8];
            acc2[n] = __builtin_amdgcn_mfma_f32_16x16x32_bf16(a2, b2f, acc2[n], 0, 0, 0);
        }
    }

    // ---------- scatter-add local_embed into agg[b, dst, :] ----------
    #pragma unroll
    for (int n = 0; n < 4; ++n) {
        const float bb = b2[n * 16 + llo];
        #pragma unroll
        for (int i = 0; i < 4; ++i) {
            int row = wave * 16 + lhi * 4 + i;
            int d   = dstS[row];
            atomicAdd(&agg[(((size_t)b * NAg + d) << 6) + n * 16 + llo], acc2[n][i] + bb);
        }
    }
}

// ---- node pipeline (fp32, small): out = (relu([x0|x_last|agg] @ W1 + b1)) @ W2 + b2 ----
__global__ __launch_bounds__(256) void node_kernel(
    const float* __restrict__ x0, const float* __restrict__ x_last,
    const float* __restrict__ agg, const float* __restrict__ w1,
    const float* __restrict__ b1, const float* __restrict__ w2,
    const float* __restrict__ b2, float* __restrict__ out)
{
    __shared__ float lf[16][160];
    __shared__ float h2s[16][257];
    const int tid = threadIdx.x;
    const int r0  = blockIdx.x * 16;   // global node-row = b*128 + a

    for (int idx = tid; idx < 16 * 160; idx += 256) {
        int r = idx / 160, c = idx % 160;
        int gr = r0 + r;
        int bb = gr >> 7, a = gr & 127;
        float v;
        if (c < 32)      v = x0[(((size_t)bb * NAg + a) << 5) + c];
        else if (c < 96) v = x_last[(((size_t)bb * NAg + a) << 6) + (c - 32)];
        else             v = agg[((size_t)gr << 6) + (c - 96)];
        lf[r][c] = v;
    }
    __syncthreads();

    {   // layer 1: thread == output column
        const int c = tid;
        float acc[16];
        const float bb = b1[c];
        #pragma unroll
        for (int r = 0; r < 16; ++r) acc[r] = bb;
        for (int k = 0; k < 160; ++k) {
            float wv = w1[k * 256 + c];
            #pragma unroll
            for (int r = 0; r < 16; ++r) acc[r] = fmaf(lf[r][k], wv, acc[r]);
        }
        #pragma unroll
        for (int r = 0; r < 16; ++r) h2s[r][c] = fmaxf(acc[r], 0.f);
    }
    __syncthreads();

    {   // layer 2: thread -> (n = tid&63, 4 rows)
        const int n = tid & 63, rq = tid >> 6;
        float acc[4];
        const float bb = b2[n];
        #pragma unroll
        for (int j = 0; j < 4; ++j) acc[j] = bb;
        for (int k = 0; k < 256; ++k) {
            float wv = w2[k * 64 + n];
            #pragma unroll
            for (int j = 0; j < 4; ++j) acc[j] = fmaf(h2s[rq * 4 + j][k], wv, acc[j]);
        }
        #pragma unroll
        for (int j = 0; j < 4; ++j)
            out[((size_t)(r0 + rq * 4 + j) << 6) + n] = acc[j];
    }
}

extern "C" void kernel_launch(void* const* d_in, const int* in_sizes, int n_in,
                              void* d_out, int out_size, void* d_ws, size_t ws_size,
                              hipStream_t stream)
{
    const float* x0       = (const float*)d_in[0];
    const float* x_last   = (const float*)d_in[1];
    const float* edge_attr= (const float*)d_in[2];
    const float* conv_w   = (const float*)d_in[3];
    const float* conv_b   = (const float*)d_in[4];
    const float* mlp1_w1  = (const float*)d_in[5];
    const float* mlp1_b1  = (const float*)d_in[6];
    const float* mlp1_w2  = (const float*)d_in[7];
    const float* mlp1_b2  = (const float*)d_in[8];
    const float* mlp2_w1  = (const float*)d_in[9];
    const float* mlp2_b1  = (const float*)d_in[10];
    const float* mlp2_w2  = (const float*)d_in[11];
    const float* mlp2_b2  = (const float*)d_in[12];
    const int*   edge_idx = (const int*)d_in[13];

    char* ws = (char*)d_ws;
    float* agg           = (float*)ws;                                  // 1 MB
    unsigned short* w1p  = (unsigned short*)(ws + (1 << 20));           // 160 KB
    unsigned short* w2p  = (unsigned short*)(ws + (1 << 20) + 160 * 1024); // 32 KB

    hipMemsetAsync(agg, 0, (size_t)BSg * NAg * EMBg * sizeof(float), stream);
    pack_weights<<<320, 256, 0, stream>>>(mlp1_w1, mlp1_w2, w1p, w2p);
    edge_kernel<<<BSg * NTILES, 256, 0, stream>>>(x0, x_last, edge_attr, conv_w, conv_b,
                                                  w1p, mlp1_b1, w2p, mlp1_b2, edge_idx, agg);
    node_kernel<<<(BSg * NAg) / 16, 256, 0, stream>>>(x0, x_last, agg, mlp2_w1, mlp2_b1,
                                                      mlp2_w2, mlp2_b2, (float*)d_out);
}